// Round 7
// baseline (353.999 us; speedup 1.0000x reference)
//
#include <hip/hip_runtime.h>
#include <hip/hip_bf16.h>
#include <math.h>

// Problem constants
#define B_    32
#define IC    512
#define OC    256
#define HW    32
#define OHW   64

// ws layout:
//   xcl  at offset 0:          bf16 [32][34][34][512]  = 37,879,808 B (zero-padded channels-last)
//   Amat at offset 37,879,808: bf16 [1024][4608]       =  9,437,184 B
#define WS_AMAT_OFF 37879808ull

typedef __attribute__((ext_vector_type(8))) short short8;
typedef __attribute__((ext_vector_type(16))) float f32x16;
typedef __attribute__((ext_vector_type(2))) float f32x2;

#define GPTR(x) ((const __attribute__((address_space(1))) char*)(x))
#define LPTR(x) ((__attribute__((address_space(3))) char*)(x))

// ---------------------------------------------------------------------------
// Weight transform. M-row order (oc*4 + p): reg-quads of the 32x32 MFMA C
// layout (row = (reg&3) + 8*(reg>>2) + 4*(lane>>5)) are the 4 parities of one
// oc -> coalesced 2x2 output quads in the epilogue.
__global__ __launch_bounds__(256) void wtrans(const float* __restrict__ w,
                                              __hip_bfloat16* __restrict__ Amat) {
    int t = blockIdx.x * blockDim.x + threadIdx.x;  // 131072 threads
    int ic = t & 511, oc = t >> 9;

    const float gain = 1.0f / sqrtf((float)(IC * 9));
    float wl[3][3];
    const float* wp = w + ((size_t)oc * IC + ic) * 9;
#pragma unroll
    for (int i = 0; i < 3; ++i)
#pragma unroll
        for (int j = 0; j < 3; ++j) wl[i][j] = wp[i * 3 + j] * gain;

    const float f1[4] = {1.f, 3.f, 3.f, 1.f};
    float g2[6][6];
#pragma unroll
    for (int s = 0; s < 6; ++s)
#pragma unroll
        for (int tt = 0; tt < 6; ++tt) {
            float acc = 0.f;
#pragma unroll
            for (int i = 0; i < 3; ++i)
#pragma unroll
                for (int j = 0; j < 3; ++j) {
                    int a = s - 2 + i, b = tt - 2 + j;
                    if (a >= 0 && a < 4 && b >= 0 && b < 4)
                        acc += wl[i][j] * f1[a] * f1[b] * 0.0625f;
                }
            g2[s][tt] = acc;
        }

#pragma unroll
    for (int pm = 0; pm < 2; ++pm)
#pragma unroll
        for (int pn = 0; pn < 2; ++pn)
#pragma unroll
            for (int k = 0; k < 3; ++k)
#pragma unroll
                for (int l = 0; l < 3; ++l) {
                    int p = pm * 2 + pn;
                    size_t idx = ((size_t)(oc * 4 + p) * 4608) + (k * 3 + l) * 512 + ic;
                    Amat[idx] = __float2bfloat16(g2[2 * k + 1 - pm][2 * l + 1 - pn]);
                }
}

// ---------------------------------------------------------------------------
// x (fp32 NCHW) -> xcl (bf16, [b][34][34][512], zero halo), via LDS transpose.
__global__ __launch_bounds__(256) void xprep(const float* __restrict__ x,
                                             __hip_bfloat16* __restrict__ xcl) {
    int blk = blockIdx.x;            // 32*34 blocks
    int b = blk / 34, h = blk % 34;
    __hip_bfloat16* orow = xcl + (size_t)(b * 34 + h) * 34 * 512;
    int t = threadIdx.x;
    bool hin = (h >= 1 && h <= 32);

    for (int i = t; i < 2 * 512; i += 256) {
        int wsel = i >> 9, ic = i & 511;
        orow[(size_t)(wsel * 33) * 512 + ic] = __float2bfloat16(0.f);
    }

    __shared__ float ls[16][33];
    int icl_r = t >> 5, wv_r = t & 31;
    int wv_w = t >> 3, icl_w = t & 7;

    for (int ic0 = 0; ic0 < 512; ic0 += 16) {
        __syncthreads();
#pragma unroll
        for (int pp = 0; pp < 2; ++pp) {
            int icll = icl_r + pp * 8;
            float v = 0.f;
            if (hin) v = x[(((size_t)b * IC + ic0 + icll) * HW + (h - 1)) * HW + wv_r];
            ls[icll][wv_r] = v;
        }
        __syncthreads();
#pragma unroll
        for (int pp = 0; pp < 2; ++pp) {
            int icll = icl_w + pp * 8;
            orow[(size_t)(wv_w + 1) * 512 + ic0 + icll] = __float2bfloat16(ls[icll][wv_w]);
        }
    }
}

// ---------------------------------------------------------------------------
// Implicit-GEMM, 256x256 tile, BK=32, 8 waves (2Mx4N), ring-4 LDS, counted
// vmcnt(4) (R4's verified accounting), T2 granule swizzle, T5 setprio.
// THIS ROUND: inner engine = mfma_f32_32x32x16_bf16 (2495 TF ceiling vs 2075
// for 16x16, m119) — 16 MFMA/wave/K32 instead of 32, same LDS traffic.
// Per-wave output 128x64 = 4Mfrag x 2Nfrag of 32x32, acc = 8 x f32x16.
//
// LDS buffer (32 KB): A[256 rows][64 B] then B at +16384. Rows = 4 granules
// of 16 B; granule g stored at slot g ^ (r&3) (both-sides swizzle).
__global__ __launch_bounds__(512, 2) void gemm_conv(const __hip_bfloat16* __restrict__ Amat,
                                                    const __hip_bfloat16* __restrict__ xcl,
                                                    const float* __restrict__ bias,
                                                    float* __restrict__ out) {
    __shared__ __align__(1024) char lds[4 * 32768];

    const int NT = 144;              // K-tiles of 32 (K = 4608)
    int bid = blockIdx.x;
    // XCD remap: all 4 mt sharing a B-panel land on one XCD (bid%8), and the
    // 16 consecutive blocks of one (xcd, mt) sweep nt -> A-panel L2-hot.
    int mt = bid >> 7;               // 0..3
    int nt = (bid & 7) * 16 + ((bid >> 3) & 15);  // 0..127
    int tid = threadIdx.x;
    int wid = tid >> 6;
    int lane = tid & 63;
    int wr = wid >> 2;               // 0..1  (M half: rows wr*128..+127)
    int wc = wid & 3;                // 0..3  (N quarter: cols wc*64..+63)
    int ln31 = lane & 31;
    int hi = lane >> 5;              // k-group half within MFMA K=16

    // ---- staging thread constants (swizzle folded into global source) ----
    int r_ = tid >> 2;               // 0..127 (chunk rows; second chunk +128)
    int slt = tid & 3;               // LDS slot
    int g_ = slt ^ (r_ & 3);         // global granule fetched into slot slt

    const char* GA = (const char*)Amat;
    const char* GB = (const char*)xcl;

    int asrc[2], bsrc[2];
#pragma unroll
    for (int i = 0; i < 2; ++i) {
        int rr = i * 128 + r_;                          // 0..255 tile-local row
        asrc[i] = (mt * 256 + rr) * 9216 + g_ * 16;     // Amat row pitch 9216 B
        int n = nt * 256 + rr;
        int bb = n >> 10, uu = (n >> 5) & 31, vv = n & 31;
        bsrc[i] = (((bb * 34 + uu) * 34) + vv) * 1024 + g_ * 16;
    }
    int dA0 = wid * 1024;            // + lane*16 by HW
    int dA1 = 8192 + wid * 1024;
    int dB0 = 16384 + wid * 1024;
    int dB1 = 24576 + wid * 1024;

    // ---- ds_read bases: frag row r, granule q = 2*ks + hi, slot q^(r&3) ----
    int Abase[2], Bbase[2];
#pragma unroll
    for (int ks = 0; ks < 2; ++ks) {
        int xo = ((2 * ks + hi) ^ (ln31 & 3)) << 4;
        Abase[ks] = (wr * 128 + ln31) * 64 + xo;           // + mf*2048 imm
        Bbase[ks] = 16384 + (wc * 64 + ln31) * 64 + xo;    // + nf*2048 imm
    }

    f32x16 acc[4][2];
#pragma unroll
    for (int mf = 0; mf < 4; ++mf)
#pragma unroll
        for (int nf = 0; nf < 2; ++nf)
#pragma unroll
            for (int e = 0; e < 16; ++e) acc[mf][nf][e] = 0.f;

    auto STAGE = [&](int ks, int bufi) {
        int kl = ks >> 4;
        int kh = (kl * 11) >> 5;     // kl/3 for kl in [0,9)
        int kw = kl - 3 * kh;
        int bo = (kh * 34 + kw) * 1024 + (ks & 15) * 64;
        int ao = ks * 64;
        char* L = lds + bufi * 32768;
        __builtin_amdgcn_global_load_lds(GPTR(GA + asrc[0] + ao), LPTR(L + dA0), 16, 0, 0);
        __builtin_amdgcn_global_load_lds(GPTR(GA + asrc[1] + ao), LPTR(L + dA1), 16, 0, 0);
        __builtin_amdgcn_global_load_lds(GPTR(GB + bsrc[0] + bo), LPTR(L + dB0), 16, 0, 0);
        __builtin_amdgcn_global_load_lds(GPTR(GB + bsrc[1] + bo), LPTR(L + dB1), 16, 0, 0);
    };

    // prologue: fill pipeline depth 2
    STAGE(0, 0);
    STAGE(1, 1);

    for (int t = 0; t < NT; ++t) {
        // counted wait: keep tile t+1's 4 loads in flight; tile t landed
        asm volatile("s_waitcnt vmcnt(4)" ::: "memory");
        __builtin_amdgcn_s_barrier();
        __builtin_amdgcn_sched_barrier(0);

        STAGE(t + 2 < NT ? t + 2 : NT - 1, (t + 2) & 3);

        const char* Lc = lds + (t & 3) * 32768;
        short8 aF[2][4], bF[2][2];
#pragma unroll
        for (int ks = 0; ks < 2; ++ks) {
#pragma unroll
            for (int nf = 0; nf < 2; ++nf)
                bF[ks][nf] = *(const short8*)(Lc + Bbase[ks] + nf * 2048);
#pragma unroll
            for (int mf = 0; mf < 4; ++mf)
                aF[ks][mf] = *(const short8*)(Lc + Abase[ks] + mf * 2048);
        }

        __builtin_amdgcn_s_setprio(1);
#pragma unroll
        for (int ks = 0; ks < 2; ++ks)
#pragma unroll
            for (int mf = 0; mf < 4; ++mf)
#pragma unroll
                for (int nf = 0; nf < 2; ++nf)
                    acc[mf][nf] = __builtin_amdgcn_mfma_f32_32x32x16_bf16(
                        aF[ks][mf], bF[ks][nf], acc[mf][nf], 0, 0, 0);
        __builtin_amdgcn_s_setprio(0);
    }
    asm volatile("s_waitcnt vmcnt(0)" ::: "memory");   // drain clamped stages

    // ---- epilogue: C row = (reg&3) + 8*(reg>>2) + 4*hi; M-row = oc*4+p ----
    const float s2 = 1.41421356237309515f;
#pragma unroll
    for (int mf = 0; mf < 4; ++mf) {
#pragma unroll
        for (int nf = 0; nf < 2; ++nf) {
            int n = nt * 256 + wc * 64 + nf * 32 + ln31;
            int b = n >> 10, u = (n >> 5) & 31, v = n & 31;
#pragma unroll
            for (int g = 0; g < 4; ++g) {
                int oc = mt * 64 + wr * 32 + mf * 8 + 2 * g + hi;
                float bv = bias[oc];
                float y0 = acc[mf][nf][4 * g + 0] + bv;   // p=0: (pm,pn)=(0,0)
                float y1 = acc[mf][nf][4 * g + 1] + bv;   // p=1: (0,1)
                float y2 = acc[mf][nf][4 * g + 2] + bv;   // p=2: (1,0)
                float y3 = acc[mf][nf][4 * g + 3] + bv;   // p=3: (1,1)
                y0 = (y0 >= 0.f ? y0 : 0.2f * y0) * s2;
                y1 = (y1 >= 0.f ? y1 : 0.2f * y1) * s2;
                y2 = (y2 >= 0.f ? y2 : 0.2f * y2) * s2;
                y3 = (y3 >= 0.f ? y3 : 0.2f * y3) * s2;
                size_t base = (((size_t)b * OC + oc) * OHW + 2 * u) * OHW + 2 * v;
                *(f32x2*)(out + base)       = (f32x2){y0, y1};
                *(f32x2*)(out + base + OHW) = (f32x2){y2, y3};
            }
        }
    }
}

// ---------------------------------------------------------------------------
extern "C" void kernel_launch(void* const* d_in, const int* in_sizes, int n_in,
                              void* d_out, int out_size, void* d_ws, size_t ws_size,
                              hipStream_t stream) {
    const float* x    = (const float*)d_in[0];
    const float* w    = (const float*)d_in[1];
    const float* bias = (const float*)d_in[2];
    float* out = (float*)d_out;

    __hip_bfloat16* xcl  = (__hip_bfloat16*)d_ws;
    __hip_bfloat16* Amat = (__hip_bfloat16*)((char*)d_ws + WS_AMAT_OFF);

    xprep<<<32 * 34, 256, 0, stream>>>(x, xcl);
    wtrans<<<(OC * IC) / 256, 256, 0, stream>>>(w, Amat);
    // grid: 4 M-tiles * 128 N-tiles = 512 blocks, 512 threads
    gemm_conv<<<512, 512, 0, stream>>>(Amat, xcl, bias, out);
}

// Round 8
// 315.475 us; speedup vs baseline: 1.1221x; 1.1221x over previous
//
#include <hip/hip_runtime.h>
#include <hip/hip_bf16.h>
#include <math.h>

// Problem constants
#define B_    32
#define IC    512
#define OC    256
#define HW    32
#define OHW   64

// ws layout:
//   xcl  at offset 0:          bf16 [32][34][34][512]  = 37,879,808 B (zero-padded channels-last)
//   Amat at offset 37,879,808: bf16 [1024][4608]       =  9,437,184 B
#define WS_AMAT_OFF 37879808ull

typedef __attribute__((ext_vector_type(8))) short short8;
typedef __attribute__((ext_vector_type(16))) float f32x16;
typedef __attribute__((ext_vector_type(2))) float f32x2;

#define GPTR(x) ((const __attribute__((address_space(1))) char*)(x))
#define LPTR(x) ((__attribute__((address_space(3))) char*)(x))

// ---------------------------------------------------------------------------
// Weight transform. M-row order (oc*4 + p): reg-quads of the 32x32 MFMA C
// layout (row = (reg&3) + 8*(reg>>2) + 4*(lane>>5)) are the 4 parities of one
// oc -> coalesced 2x2 output quads in the epilogue.
__global__ __launch_bounds__(256) void wtrans(const float* __restrict__ w,
                                              __hip_bfloat16* __restrict__ Amat) {
    int t = blockIdx.x * blockDim.x + threadIdx.x;  // 131072 threads
    int ic = t & 511, oc = t >> 9;

    const float gain = 1.0f / sqrtf((float)(IC * 9));
    float wl[3][3];
    const float* wp = w + ((size_t)oc * IC + ic) * 9;
#pragma unroll
    for (int i = 0; i < 3; ++i)
#pragma unroll
        for (int j = 0; j < 3; ++j) wl[i][j] = wp[i * 3 + j] * gain;

    const float f1[4] = {1.f, 3.f, 3.f, 1.f};
    float g2[6][6];
#pragma unroll
    for (int s = 0; s < 6; ++s)
#pragma unroll
        for (int tt = 0; tt < 6; ++tt) {
            float acc = 0.f;
#pragma unroll
            for (int i = 0; i < 3; ++i)
#pragma unroll
                for (int j = 0; j < 3; ++j) {
                    int a = s - 2 + i, b = tt - 2 + j;
                    if (a >= 0 && a < 4 && b >= 0 && b < 4)
                        acc += wl[i][j] * f1[a] * f1[b] * 0.0625f;
                }
            g2[s][tt] = acc;
        }

#pragma unroll
    for (int pm = 0; pm < 2; ++pm)
#pragma unroll
        for (int pn = 0; pn < 2; ++pn)
#pragma unroll
            for (int k = 0; k < 3; ++k)
#pragma unroll
                for (int l = 0; l < 3; ++l) {
                    int p = pm * 2 + pn;
                    size_t idx = ((size_t)(oc * 4 + p) * 4608) + (k * 3 + l) * 512 + ic;
                    Amat[idx] = __float2bfloat16(g2[2 * k + 1 - pm][2 * l + 1 - pn]);
                }
}

// ---------------------------------------------------------------------------
// x (fp32 NCHW) -> xcl (bf16, [b][34][34][512], zero halo), via LDS transpose.
__global__ __launch_bounds__(256) void xprep(const float* __restrict__ x,
                                             __hip_bfloat16* __restrict__ xcl) {
    int blk = blockIdx.x;            // 32*34 blocks
    int b = blk / 34, h = blk % 34;
    __hip_bfloat16* orow = xcl + (size_t)(b * 34 + h) * 34 * 512;
    int t = threadIdx.x;
    bool hin = (h >= 1 && h <= 32);

    for (int i = t; i < 2 * 512; i += 256) {
        int wsel = i >> 9, ic = i & 511;
        orow[(size_t)(wsel * 33) * 512 + ic] = __float2bfloat16(0.f);
    }

    __shared__ float ls[16][33];
    int icl_r = t >> 5, wv_r = t & 31;
    int wv_w = t >> 3, icl_w = t & 7;

    for (int ic0 = 0; ic0 < 512; ic0 += 16) {
        __syncthreads();
#pragma unroll
        for (int pp = 0; pp < 2; ++pp) {
            int icll = icl_r + pp * 8;
            float v = 0.f;
            if (hin) v = x[(((size_t)b * IC + ic0 + icll) * HW + (h - 1)) * HW + wv_r];
            ls[icll][wv_r] = v;
        }
        __syncthreads();
#pragma unroll
        for (int pp = 0; pp < 2; ++pp) {
            int icll = icl_w + pp * 8;
            orow[(size_t)(wv_w + 1) * 512 + ic0 + icll] = __float2bfloat16(ls[icll][wv_w]);
        }
    }
}

// ---------------------------------------------------------------------------
// Implicit-GEMM, 256x256 tile, BK=32, 8 waves (2Mx4N), ring-4 LDS, counted
// vmcnt(4), T2 granule swizzle, T5 setprio, 32x32x16 MFMA engine.
// SWIZZLE FIX (R8): slot = g ^ ((r>>1)&3), NOT g ^ (r&3). LSB of (r&3)
// equals row parity, which also selects the bank half -> 4-way conflicts
// (R7: 8.5e7 = +1152 cyc/block-tile). (r>>1)&3 decorrelates -> 2-way (free),
// verified zero-conflict in R4.
//
// LDS buffer (32 KB): A[256 rows][64 B] then B at +16384. Rows = 4 granules
// of 16 B; granule g stored at slot g ^ ((r>>1)&3) (both-sides swizzle).
__global__ __launch_bounds__(512, 2) void gemm_conv(const __hip_bfloat16* __restrict__ Amat,
                                                    const __hip_bfloat16* __restrict__ xcl,
                                                    const float* __restrict__ bias,
                                                    float* __restrict__ out) {
    __shared__ __align__(1024) char lds[4 * 32768];

    const int NT = 144;              // K-tiles of 32 (K = 4608)
    int bid = blockIdx.x;
    // XCD remap (verified R7: FETCH 610->281 MB): all 4 mt sharing a B-panel
    // land on one XCD (bid%8); 16 consecutive blocks sweep nt -> A-panel hot.
    int mt = bid >> 7;               // 0..3
    int nt = (bid & 7) * 16 + ((bid >> 3) & 15);  // 0..127
    int tid = threadIdx.x;
    int wid = tid >> 6;
    int lane = tid & 63;
    int wr = wid >> 2;               // 0..1  (M half: rows wr*128..+127)
    int wc = wid & 3;                // 0..3  (N quarter: cols wc*64..+63)
    int ln31 = lane & 31;
    int hi = lane >> 5;              // k-group half within MFMA K=16

    // ---- staging thread constants (swizzle folded into global source) ----
    int r_ = tid >> 2;               // 0..127 (chunk rows; second chunk +128)
    int slt = tid & 3;               // LDS slot
    int g_ = slt ^ ((r_ >> 1) & 3);  // FIXED involution (was slt ^ (r_&3))

    const char* GA = (const char*)Amat;
    const char* GB = (const char*)xcl;

    int asrc[2], bsrc[2];
#pragma unroll
    for (int i = 0; i < 2; ++i) {
        int rr = i * 128 + r_;                          // 0..255 tile-local row
        asrc[i] = (mt * 256 + rr) * 9216 + g_ * 16;     // Amat row pitch 9216 B
        int n = nt * 256 + rr;
        int bb = n >> 10, uu = (n >> 5) & 31, vv = n & 31;
        bsrc[i] = (((bb * 34 + uu) * 34) + vv) * 1024 + g_ * 16;
    }
    int dA0 = wid * 1024;            // + lane*16 by HW
    int dA1 = 8192 + wid * 1024;
    int dB0 = 16384 + wid * 1024;
    int dB1 = 24576 + wid * 1024;

    // ---- ds_read bases: frag row r, granule q = 2*ks + hi, slot q^((r>>1)&3) ----
    int Abase[2], Bbase[2];
#pragma unroll
    for (int ks = 0; ks < 2; ++ks) {
        int xo = ((2 * ks + hi) ^ ((ln31 >> 1) & 3)) << 4;  // FIXED
        Abase[ks] = (wr * 128 + ln31) * 64 + xo;           // + mf*2048 imm
        Bbase[ks] = 16384 + (wc * 64 + ln31) * 64 + xo;    // + nf*2048 imm
    }

    f32x16 acc[4][2];
#pragma unroll
    for (int mf = 0; mf < 4; ++mf)
#pragma unroll
        for (int nf = 0; nf < 2; ++nf)
#pragma unroll
            for (int e = 0; e < 16; ++e) acc[mf][nf][e] = 0.f;

    auto STAGE = [&](int ks, int bufi) {
        int kl = ks >> 4;
        int kh = (kl * 11) >> 5;     // kl/3 for kl in [0,9)
        int kw = kl - 3 * kh;
        int bo = (kh * 34 + kw) * 1024 + (ks & 15) * 64;
        int ao = ks * 64;
        char* L = lds + bufi * 32768;
        __builtin_amdgcn_global_load_lds(GPTR(GA + asrc[0] + ao), LPTR(L + dA0), 16, 0, 0);
        __builtin_amdgcn_global_load_lds(GPTR(GA + asrc[1] + ao), LPTR(L + dA1), 16, 0, 0);
        __builtin_amdgcn_global_load_lds(GPTR(GB + bsrc[0] + bo), LPTR(L + dB0), 16, 0, 0);
        __builtin_amdgcn_global_load_lds(GPTR(GB + bsrc[1] + bo), LPTR(L + dB1), 16, 0, 0);
    };

    // prologue: fill pipeline depth 2
    STAGE(0, 0);
    STAGE(1, 1);

    for (int t = 0; t < NT; ++t) {
        // counted wait: keep tile t+1's 4 loads in flight; tile t landed
        asm volatile("s_waitcnt vmcnt(4)" ::: "memory");
        __builtin_amdgcn_s_barrier();
        __builtin_amdgcn_sched_barrier(0);

        STAGE(t + 2 < NT ? t + 2 : NT - 1, (t + 2) & 3);

        const char* Lc = lds + (t & 3) * 32768;
        short8 aF[2][4], bF[2][2];
#pragma unroll
        for (int ks = 0; ks < 2; ++ks) {
#pragma unroll
            for (int nf = 0; nf < 2; ++nf)
                bF[ks][nf] = *(const short8*)(Lc + Bbase[ks] + nf * 2048);
#pragma unroll
            for (int mf = 0; mf < 4; ++mf)
                aF[ks][mf] = *(const short8*)(Lc + Abase[ks] + mf * 2048);
        }

        __builtin_amdgcn_s_setprio(1);
#pragma unroll
        for (int ks = 0; ks < 2; ++ks)
#pragma unroll
            for (int mf = 0; mf < 4; ++mf)
#pragma unroll
                for (int nf = 0; nf < 2; ++nf)
                    acc[mf][nf] = __builtin_amdgcn_mfma_f32_32x32x16_bf16(
                        aF[ks][mf], bF[ks][nf], acc[mf][nf], 0, 0, 0);
        __builtin_amdgcn_s_setprio(0);
    }
    asm volatile("s_waitcnt vmcnt(0)" ::: "memory");   // drain clamped stages

    // ---- epilogue: C row = (reg&3) + 8*(reg>>2) + 4*hi; M-row = oc*4+p ----
    const float s2 = 1.41421356237309515f;
#pragma unroll
    for (int mf = 0; mf < 4; ++mf) {
#pragma unroll
        for (int nf = 0; nf < 2; ++nf) {
            int n = nt * 256 + wc * 64 + nf * 32 + ln31;
            int b = n >> 10, u = (n >> 5) & 31, v = n & 31;
#pragma unroll
            for (int g = 0; g < 4; ++g) {
                int oc = mt * 64 + wr * 32 + mf * 8 + 2 * g + hi;
                float bv = bias[oc];
                float y0 = acc[mf][nf][4 * g + 0] + bv;   // p=0: (pm,pn)=(0,0)
                float y1 = acc[mf][nf][4 * g + 1] + bv;   // p=1: (0,1)
                float y2 = acc[mf][nf][4 * g + 2] + bv;   // p=2: (1,0)
                float y3 = acc[mf][nf][4 * g + 3] + bv;   // p=3: (1,1)
                y0 = (y0 >= 0.f ? y0 : 0.2f * y0) * s2;
                y1 = (y1 >= 0.f ? y1 : 0.2f * y1) * s2;
                y2 = (y2 >= 0.f ? y2 : 0.2f * y2) * s2;
                y3 = (y3 >= 0.f ? y3 : 0.2f * y3) * s2;
                size_t base = (((size_t)b * OC + oc) * OHW + 2 * u) * OHW + 2 * v;
                *(f32x2*)(out + base)       = (f32x2){y0, y1};
                *(f32x2*)(out + base + OHW) = (f32x2){y2, y3};
            }
        }
    }
}

// ---------------------------------------------------------------------------
extern "C" void kernel_launch(void* const* d_in, const int* in_sizes, int n_in,
                              void* d_out, int out_size, void* d_ws, size_t ws_size,
                              hipStream_t stream) {
    const float* x    = (const float*)d_in[0];
    const float* w    = (const float*)d_in[1];
    const float* bias = (const float*)d_in[2];
    float* out = (float*)d_out;

    __hip_bfloat16* xcl  = (__hip_bfloat16*)d_ws;
    __hip_bfloat16* Amat = (__hip_bfloat16*)((char*)d_ws + WS_AMAT_OFF);

    xprep<<<32 * 34, 256, 0, stream>>>(x, xcl);
    wtrans<<<(OC * IC) / 256, 256, 0, stream>>>(w, Amat);
    // grid: 4 M-tiles * 128 N-tiles = 512 blocks, 512 threads
    gemm_conv<<<512, 512, 0, stream>>>(Amat, xcl, bias, out);
}